// Round 1
// baseline (195.505 us; speedup 1.0000x reference)
//
#include <hip/hip_runtime.h>
#include <hip/hip_cooperative_groups.h>
#include <math.h>

#define NQ 512
#define NC 8000
#define DNUM 6
#define NBINS 50
#define DCAT 20
#define DENC 26      // DNUM + DCAT
#define DOUT 10
#define CHUNK 1000
#define NCHUNK 8
#define NBLK 256
#define NTHR 512
#define GSIZE (NBLK * NTHR)

// ============================================================================
// Fused cooperative kernel.
//
// THEORY OF RECORD (round 1): rocprof top-5 shows the timed region is
// dominated by two 256 MiB harness poison fills (2 x 40.2 us @ 6.6 TB/s).
// Our kernels model at ~4 us (encode) + ~8 us (nca). Fusing into one
// cooperative launch removes one graph node + gap; register ping-pong
// prefetch hides per-chunk L2 latency at 2 waves/SIMD.
//
// Phase 1 (encode): G_f(v) = sum_j ceil((v - u_fj*delta_fj)/delta_fj).
// Each per-bin map is fp-monotone in v, so all 50 bin diffs for a feature
// share sign => sum_j |bin_j(x)-bin_j(c)| == |G_f(x)-G_f(c)| exactly
// (integer-valued floats, sums << 2^24). 320-dim L1 -> 26-dim L1.
// Grid-strided over all 131072 threads (2 iters), identical fp op order
// to the verified standalone encode kernel.
//
// Phase 2 (nca): block = 2 queries x all 8000 candidates. 500 of 512
// threads own 2 candidates (float2 columns). Class sums accumulate in
// registers across all 8 chunks (one end-of-kernel butterfly); per-chunk
// lse via wave min-shift + LDS wave-partial combine (exact logsumexp).
// ============================================================================
__global__ __launch_bounds__(NTHR) void fused(
    const float* __restrict__ c_num, const float* __restrict__ c_cat,
    const float* __restrict__ x_num, const float* __restrict__ x_cat,
    const float* __restrict__ delta, const float* __restrict__ u,
    const int* __restrict__ cy,
    float* __restrict__ cEnc, float* __restrict__ qEnc,
    float* __restrict__ out) {

    const int tid = threadIdx.x;
    const int gtid = blockIdx.x * NTHR + tid;

    // ---------------- phase 1: encode ----------------
    const int nA = (NC + NQ) * DNUM;            // 51072
    const int nTot = nA + (NC + NQ) * DCAT;     // 221312
    for (int i = gtid; i < nTot; i += GSIZE) {
        if (i < nA) {
            int f = i % DNUM, p = i / DNUM;
            bool is_c = p < NC;
            int idx = is_c ? p : p - NC;
            float v = (is_c ? c_num : x_num)[idx * DNUM + f];
            float g = 0.f;
            for (int j = 0; j < NBINS; ++j) {
                // exact reference op order: scaled_u = u*delta; ceil((v-sc)/delta)
                float dl = delta[f * NBINS + j];
                float sc = u[f * NBINS + j] * dl;
                g += ceilf((v - sc) / dl);
            }
            if (is_c) cEnc[f * NC + idx] = g;
            else      qEnc[f * NQ + idx] = g;
        } else {
            int i2 = i - nA;
            int k = i2 % DCAT, p = i2 / DCAT;
            bool is_c = p < NC;
            int idx = is_c ? p : p - NC;
            float v = (is_c ? c_cat : x_cat)[idx * DCAT + k];
            if (is_c) cEnc[(DNUM + k) * NC + idx] = v;
            else      qEnc[(DNUM + k) * NQ + idx] = v;
        }
    }
    __threadfence();
    cooperative_groups::this_grid().sync();

    // ---------------- phase 2: nca ----------------
    __shared__ float xs[DENC * 2];              // 52
    __shared__ float ms_parts[NCHUNK * 8 * 4];  // [chunk][wave][m0,s0,m1,s1]
    __shared__ float cls_parts[8][2 * DOUT];    // [wave][q*10+k]
    __shared__ float tmp[2][NCHUNK];
    __shared__ float lse_sh[2];

    const int q0 = blockIdx.x * 2;
    if (tid < DENC * 2) {
        int d = tid >> 1, q = tid & 1;
        xs[tid] = qEnc[d * NQ + q0 + q];
    }
    __syncthreads();

    // queries -> registers (no in-loop LDS reads)
    float xr0[DENC], xr1[DENC];
#pragma unroll
    for (int d = 0; d < DENC; ++d) { xr0[d] = xs[2 * d]; xr1[d] = xs[2 * d + 1]; }

    const bool act = tid < 500;                 // 500 * 2 = 1000 candidates
    const int cl = act ? 2 * tid : 996;         // clamp inactive to safe addr
    const int lane = tid & 63, wave = tid >> 6;

    float cls[2 * DOUT];                        // per-thread class sums, all chunks
#pragma unroll
    for (int k = 0; k < 2 * DOUT; ++k) cls[k] = 0.f;

    float2 bufA[DENC], bufB[DENC];              // ping-pong chunk prefetch

#define LOADC(BUF, CH) do {                                                   \
    const float* _p = cEnc + (CH) * CHUNK + cl;                               \
    _Pragma("unroll")                                                         \
    for (int d = 0; d < DENC; ++d)                                            \
        BUF[d] = *(const float2*)(_p + (size_t)d * NC);                       \
} while (0)

#define COMPUTE(BUF, CH) do {                                                 \
    int2 y = *(const int2*)(cy + (CH) * CHUNK + cl);                          \
    float a00 = 0.f, a01 = 0.f, a10 = 0.f, a11 = 0.f;   /* a[q][cand] */      \
    _Pragma("unroll")                                                         \
    for (int d = 0; d < DENC; ++d) {                                          \
        a00 += fabsf(BUF[d].x - xr0[d]); a01 += fabsf(BUF[d].y - xr0[d]);     \
        a10 += fabsf(BUF[d].x - xr1[d]); a11 += fabsf(BUF[d].y - xr1[d]);     \
    }                                                                         \
    float m0 = act ? fminf(a00, a01) : INFINITY;                              \
    float m1 = act ? fminf(a10, a11) : INFINITY;                              \
    _Pragma("unroll")                                                         \
    for (int sh = 32; sh >= 1; sh >>= 1) {                                    \
        m0 = fminf(m0, __shfl_xor(m0, sh));                                   \
        m1 = fminf(m1, __shfl_xor(m1, sh));                                   \
    }                                                                         \
    float s0 = 0.f, s1 = 0.f;                                                 \
    if (act) {                                                                \
        float e00 = __expf(-a00), e01 = __expf(-a01);                         \
        float e10 = __expf(-a10), e11 = __expf(-a11);                         \
        s0 = __expf(m0 - a00) + __expf(m0 - a01);                             \
        s1 = __expf(m1 - a10) + __expf(m1 - a11);                             \
        _Pragma("unroll")                                                     \
        for (int k = 0; k < DOUT; ++k) {                                      \
            /* mask in {0,1}: fma is bit-identical to select+add */           \
            float mx = (y.x == k) ? 1.f : 0.f;                                \
            float my = (y.y == k) ? 1.f : 0.f;                                \
            cls[k]        = fmaf(mx, e00, fmaf(my, e01, cls[k]));             \
            cls[DOUT + k] = fmaf(mx, e10, fmaf(my, e11, cls[DOUT + k]));      \
        }                                                                     \
    }                                                                         \
    _Pragma("unroll")                                                         \
    for (int sh = 32; sh >= 1; sh >>= 1) {                                    \
        s0 += __shfl_xor(s0, sh);                                             \
        s1 += __shfl_xor(s1, sh);                                             \
    }                                                                         \
    if (lane == 0) {                                                          \
        float* _q = ms_parts + ((CH) * 8 + wave) * 4;                         \
        _q[0] = m0; _q[1] = s0; _q[2] = m1; _q[3] = s1;                       \
    }                                                                         \
} while (0)

    LOADC(bufA, 0);
#pragma unroll
    for (int cc = 0; cc < NCHUNK; cc += 2) {
        LOADC(bufB, cc + 1);                    // prefetch while computing A
        COMPUTE(bufA, cc);
        if (cc + 2 < NCHUNK) LOADC(bufA, cc + 2);
        COMPUTE(bufB, cc + 1);
    }
#undef LOADC
#undef COMPUTE

    // one butterfly for the 20 class sums
#pragma unroll
    for (int k = 0; k < 2 * DOUT; ++k) {
#pragma unroll
        for (int sh = 32; sh >= 1; sh >>= 1) cls[k] += __shfl_xor(cls[k], sh);
    }
    if (lane == 0) {
#pragma unroll
        for (int k = 0; k < 2 * DOUT; ++k) cls_parts[wave][k] = cls[k];
    }
    __syncthreads();

    // per-(q,chunk) lse: combine 8 wave partials exactly
    if (tid < 16) {
        int q = tid & 1, ch = tid >> 1;
        const float* p = ms_parts + ch * 32 + 2 * q;
        float M = INFINITY;
#pragma unroll
        for (int w = 0; w < 8; ++w) M = fminf(M, p[w * 4]);
        float S = 0.f;
#pragma unroll
        for (int w = 0; w < 8; ++w) S += __expf(M - p[w * 4]) * p[w * 4 + 1];
        tmp[q][ch] = logf(S) - M;     // log(sum_c exp(-d)) for this chunk
    }
    __syncthreads();
    if (tid < 2) {
        float l = 0.f;
#pragma unroll
        for (int ch = 0; ch < NCHUNK; ++ch) l += tmp[tid][ch];  // chunk order = reference
        lse_sh[tid] = l;
    }
    __syncthreads();
    if (tid < 2 * DOUT) {
        int q = tid / DOUT, k = tid % DOUT;
        float s = 0.f;
#pragma unroll
        for (int w = 0; w < 8; ++w) s += cls_parts[w][q * DOUT + k];
        out[(q0 + q) * DOUT + k] = logf(s + 1e-8f) - lse_sh[q];
    }
}

extern "C" void kernel_launch(void* const* d_in, const int* in_sizes, int n_in,
                              void* d_out, int out_size, void* d_ws, size_t ws_size,
                              hipStream_t stream) {
    const float* x_num = (const float*)d_in[0];
    const float* x_cat = (const float*)d_in[1];
    const float* c_num = (const float*)d_in[2];
    const float* c_cat = (const float*)d_in[3];
    const int*   c_y   = (const int*)d_in[4];
    const float* delta = (const float*)d_in[5];
    const float* u     = (const float*)d_in[6];

    float* ws = (float*)d_ws;
    float* cEnc = ws;                             // 26*8000 = 208,000 floats
    float* qEnc = cEnc + (size_t)DENC * NC;       // 26*512  = 13,312
    float* outp = (float*)d_out;

    // Cooperative: 256 blocks x 512 thr = 1 block/CU (VGPR<=256 guaranteed by
    // launch_bounds(512)) -> all blocks co-resident; grid.sync() valid.
    void* args[] = {
        (void*)&c_num, (void*)&c_cat, (void*)&x_num, (void*)&x_cat,
        (void*)&delta, (void*)&u, (void*)&c_y,
        (void*)&cEnc, (void*)&qEnc, (void*)&outp
    };
    hipLaunchCooperativeKernel(reinterpret_cast<const void*>(&fused),
                               dim3(NBLK), dim3(NTHR), args, 0u, stream);
}